// Round 1
// baseline (841.085 us; speedup 1.0000x reference)
//
#include <hip/hip_runtime.h>

// PointCloudCompletionLoss: two Chamfer-L2 losses.
//   out[0] = (mean_i min_j |c_i-g_j|^2 + mean_j min_i |c_i-g_j|^2) * param_coarse
//   out[1] = (mean_i min_j |f_i-g_j|^2 + mean_j min_i |f_i-g_j|^2) * param_fine
// Inputs: coarse [4,1024,3] f32, fine [4,8192,3] f32, gt [4,8192,3] f32,
//         param_coarse int, param_fine int. Output: 2 x f32.
//
// Strategy: 4 directed min-passes. Thread = one x-point (coords in VGPRs),
// wave = one Y-chunk (chunk idx made wave-uniform via readfirstlane so the
// Y stream compiles to scalar s_loads). Block reduces min across chunks in
// LDS, wave-sums, one atomicAdd per block into d_ws accumulators.

#define BIGF 3.0e38f

__global__ void pccl_init_acc(float* acc) {
    if (threadIdx.x < 4) acc[threadIdx.x] = 0.0f;
}

// X: [B,NX,3], Y: [B,NY,3]. grid = (NX/64, B), block = 256 (= 64 lanes x 4 chunks)
__global__ __launch_bounds__(256) void pccl_min_sum(
    const float* __restrict__ X, const float* __restrict__ Y,
    int NX, int NY, float* __restrict__ acc) {
    const int b    = blockIdx.y;
    const int lane = threadIdx.x & 63;
    // wave index; readfirstlane makes it provably uniform -> Y loads go scalar
    const int wv   = __builtin_amdgcn_readfirstlane(threadIdx.x >> 6);
    const int i    = blockIdx.x * 64 + lane;

    const float* xp = X + ((size_t)b * NX + i) * 3;
    const float x0 = xp[0], x1 = xp[1], x2 = xp[2];

    const int chunk = NY >> 2;                       // 4 chunks, one per wave
    const float* __restrict__ yb = Y + ((size_t)b * NY + (size_t)wv * chunk) * 3;

    float best = BIGF;
    #pragma unroll 8
    for (int j = 0; j < chunk; ++j) {
        const float y0 = yb[j * 3 + 0];
        const float y1 = yb[j * 3 + 1];
        const float y2 = yb[j * 3 + 2];
        const float dx = x0 - y0;
        const float dy = x1 - y1;
        const float dz = x2 - y2;
        const float d  = dx * dx + dy * dy + dz * dz;
        best = fminf(best, d);
    }

    __shared__ float smem[256];
    smem[threadIdx.x] = best;
    __syncthreads();

    if (threadIdx.x < 64) {
        float m = fminf(fminf(smem[lane], smem[lane + 64]),
                        fminf(smem[lane + 128], smem[lane + 192]));
        // sum the 64 per-x mins across the wave
        #pragma unroll
        for (int off = 32; off > 0; off >>= 1)
            m += __shfl_down(m, off, 64);
        if (lane == 0) atomicAdd(acc, m);
    }
}

__global__ void pccl_finalize(const float* __restrict__ acc,
                              const int* __restrict__ pc,
                              const int* __restrict__ pf,
                              float* __restrict__ out,
                              float inv_cnt_coarse, float inv_cnt_gt) {
    if (threadIdx.x == 0) {
        const float loss_c = (acc[0] * inv_cnt_coarse + acc[1] * inv_cnt_gt) * (float)pc[0];
        const float loss_f = (acc[2] * inv_cnt_gt     + acc[3] * inv_cnt_gt) * (float)pf[0];
        out[0] = loss_c;
        out[1] = loss_f;
    }
}

extern "C" void kernel_launch(void* const* d_in, const int* in_sizes, int n_in,
                              void* d_out, int out_size, void* d_ws, size_t ws_size,
                              hipStream_t stream) {
    const float* coarse = (const float*)d_in[0];
    const float* fine   = (const float*)d_in[1];
    const float* gt     = (const float*)d_in[2];
    const int*   pc     = (const int*)d_in[3];
    const int*   pf     = (const int*)d_in[4];
    float* out = (float*)d_out;
    float* acc = (float*)d_ws;   // 4 accumulators

    const int B   = 4;
    const int Nc  = in_sizes[0] / (B * 3);   // 1024
    const int Nf  = in_sizes[1] / (B * 3);   // 8192
    const int Ng  = in_sizes[2] / (B * 3);   // 8192

    pccl_init_acc<<<1, 64, 0, stream>>>(acc);

    dim3 blk(256);
    // acc[0]: coarse -> gt (min over gt for each coarse pt)
    pccl_min_sum<<<dim3(Nc / 64, B), blk, 0, stream>>>(coarse, gt, Nc, Ng, acc + 0);
    // acc[1]: gt -> coarse
    pccl_min_sum<<<dim3(Ng / 64, B), blk, 0, stream>>>(gt, coarse, Ng, Nc, acc + 1);
    // acc[2]: fine -> gt
    pccl_min_sum<<<dim3(Nf / 64, B), blk, 0, stream>>>(fine, gt, Nf, Ng, acc + 2);
    // acc[3]: gt -> fine
    pccl_min_sum<<<dim3(Ng / 64, B), blk, 0, stream>>>(gt, fine, Ng, Nf, acc + 3);

    pccl_finalize<<<1, 64, 0, stream>>>(acc, pc, pf, out,
                                        1.0f / (float)(B * Nc),
                                        1.0f / (float)(B * Ng));
}

// Round 2
// 159.923 us; speedup vs baseline: 5.2593x; 5.2593x over previous
//
#include <hip/hip_runtime.h>

// PointCloudCompletionLoss — fused Chamfer-L2.
// Fixed sizes from the reference harness:
constexpr int B  = 4;
constexpr int NC = 1024;   // coarse pts per batch
constexpr int NF = 8192;   // fine pts per batch
constexpr int NG = 8192;   // gt pts per batch
// Directed passes (X -> min over Y):
//  p0: X=coarse(4096) Y=gt   S=32   waves  512   mins[    0..4096)
//  p1: X=gt(32768)   Y=coarse S=4   waves  512   mins[ 4096..36864)
//  p2: X=fine(32768) Y=gt    S=32   waves 4096   mins[36864..69632)
//  p3: X=gt(32768)   Y=fine  S=32   waves 4096   mins[69632..102400)
// Every wave: 64 lanes x 4 X-points each (256 X) vs a 256-point Y slice,
// Y staged into a per-wave 16B-padded LDS tile (ds_read_b128 broadcast).
// Partial mins combined via atomicMin on uint bits (valid: d >= 0).
constexpr int NMINS = 102400;          // 4096 + 3*32768
constexpr int TOTAL_WAVES = 9216;      // 512+512+4096+4096

__global__ __launch_bounds__(256) void pccl_init(unsigned* __restrict__ mins,
                                                 float* __restrict__ acc) {
    int i = blockIdx.x * 256 + threadIdx.x;
    if (i < NMINS) mins[i] = 0x7F800000u;   // +inf bits
    if (i < 4) acc[i] = 0.0f;
}

__global__ __launch_bounds__(256) void pccl_stage(
    const float* __restrict__ Xc, const float* __restrict__ Xf,
    const float* __restrict__ G, unsigned* __restrict__ mins) {
    __shared__ float4 yb[4][256];   // 16 KB: per-wave padded Y tile
    const int wv   = __builtin_amdgcn_readfirstlane(threadIdx.x >> 6);
    const int lane = threadIdx.x & 63;
    const int W    = blockIdx.x * 4 + wv;

    const float* Xp; const float* Yp;
    int NX, NY, lx, local, mbase;
    if (W < 512)        { Xp = Xc; Yp = G;  NX = NC; NY = NG; lx = 2; local = W;        mbase = 0; }
    else if (W < 1024)  { Xp = G;  Yp = Xc; NX = NG; NY = NC; lx = 5; local = W - 512;  mbase = 4096; }
    else if (W < 5120)  { Xp = Xf; Yp = G;  NX = NF; NY = NG; lx = 5; local = W - 1024; mbase = 36864; }
    else                { Xp = G;  Yp = Xf; NX = NG; NY = NF; lx = 5; local = W - 5120; mbase = 69632; }
    // xtiles = 4*(NX/256) = 1<<(lx+2); all pow2 -> shifts only
    const int xt   = local & ((1 << (lx + 2)) - 1);
    const int sp   = local >> (lx + 2);            // Y-split index
    const int b    = xt >> lx;                     // batch
    const int xoff = (xt & ((1 << lx) - 1)) << 8;  // X offset within batch

    // ---- stage 256 Y points (768 dwords) into padded LDS (wave-local) ----
    const float* ys = Yp + ((size_t)b * NY + (size_t)sp * 256) * 3;
    float* shf = (float*)&yb[wv][0];
    #pragma unroll
    for (int k = 0; k < 12; ++k) {
        const int d = lane + 64 * k;           // 0..767
        const float v = ys[d];
        const int p = d / 3;                   // const-div -> magic mul
        const int c = d - p * 3;
        shf[p * 4 + c] = v;
    }

    // ---- X coords in registers: lane owns X[xoff + lane + 64k], k=0..3 ----
    float x0[4], x1[4], x2[4], best[4];
    const float* xs = Xp + ((size_t)b * NX + xoff) * 3;
    #pragma unroll
    for (int k = 0; k < 4; ++k) {
        const int xi = lane + 64 * k;
        x0[k] = xs[xi * 3 + 0];
        x1[k] = xs[xi * 3 + 1];
        x2[k] = xs[xi * 3 + 2];
        best[k] = 3.0e38f;
    }

    // ---- inner loop: 256 Y from LDS (wave-uniform b128 broadcast) ----
    #pragma unroll 8
    for (int j = 0; j < 256; ++j) {
        const float4 y = yb[wv][j];
        #pragma unroll
        for (int k = 0; k < 4; ++k) {
            const float dx = x0[k] - y.x;
            const float dy = x1[k] - y.y;
            const float dz = x2[k] - y.z;
            const float d  = dx * dx + dy * dy + dz * dz;
            best[k] = fminf(best[k], d);
        }
    }

    // ---- combine across Y-splits: atomicMin on uint bits (d >= 0) ----
    unsigned* mp = mins + mbase + b * NX + xoff;
    #pragma unroll
    for (int k = 0; k < 4; ++k)
        atomicMin(mp + lane + 64 * k, __float_as_uint(best[k]));
}

__global__ __launch_bounds__(256) void pccl_sum(const unsigned* __restrict__ mins,
                                                float* __restrict__ acc) {
    const int blk = blockIdx.x;  // 400 blocks x 256 = 102400; segment per block
    const int p = (blk < 16) ? 0 : (blk < 144) ? 1 : (blk < 272) ? 2 : 3;
    float v = __uint_as_float(mins[blk * 256 + threadIdx.x]);
    #pragma unroll
    for (int off = 32; off > 0; off >>= 1) v += __shfl_down(v, off, 64);
    __shared__ float sm[4];
    if ((threadIdx.x & 63) == 0) sm[threadIdx.x >> 6] = v;
    __syncthreads();
    if (threadIdx.x == 0) atomicAdd(acc + p, sm[0] + sm[1] + sm[2] + sm[3]);
}

__global__ void pccl_finalize(const float* __restrict__ acc,
                              const int* __restrict__ pc,
                              const int* __restrict__ pf,
                              float* __restrict__ out) {
    if (threadIdx.x == 0) {
        const float lc = (acc[0] * (1.0f / 4096.0f) + acc[1] * (1.0f / 32768.0f)) * (float)pc[0];
        const float lf = (acc[2] * (1.0f / 32768.0f) + acc[3] * (1.0f / 32768.0f)) * (float)pf[0];
        out[0] = lc;
        out[1] = lf;
    }
}

extern "C" void kernel_launch(void* const* d_in, const int* in_sizes, int n_in,
                              void* d_out, int out_size, void* d_ws, size_t ws_size,
                              hipStream_t stream) {
    const float* coarse = (const float*)d_in[0];
    const float* fine   = (const float*)d_in[1];
    const float* gt     = (const float*)d_in[2];
    const int*   pc     = (const int*)d_in[3];
    const int*   pf     = (const int*)d_in[4];
    float* out = (float*)d_out;

    unsigned* mins = (unsigned*)d_ws;            // 102400 * 4 B
    float*    acc  = (float*)(mins + NMINS);     // 4 floats

    pccl_init<<<(NMINS + 255) / 256, 256, 0, stream>>>(mins, acc);
    pccl_stage<<<TOTAL_WAVES / 4, 256, 0, stream>>>(coarse, fine, gt, mins);
    pccl_sum<<<NMINS / 256, 256, 0, stream>>>(mins, acc);
    pccl_finalize<<<1, 64, 0, stream>>>(acc, pc, pf, out);
}